// Round 6
// baseline (4446.912 us; speedup 1.0000x reference)
//
#include <hip/hip_runtime.h>
#include <hip/hip_bf16.h>

typedef _Float16 fp16_t;
typedef _Float16 v8h __attribute__((ext_vector_type(8)));
typedef _Float16 v4h __attribute__((ext_vector_type(4)));
typedef float    v4f __attribute__((ext_vector_type(4)));

#define RELAX_LR 0.3f

// async global->LDS, 16B per lane. LDS dest = wave-uniform base + lane*16.
__device__ __forceinline__ void async_cp16(const void* g, void* l) {
    __builtin_amdgcn_global_load_lds(
        (const __attribute__((address_space(1))) void*)g,
        (__attribute__((address_space(3))) void*)l, 16, 0, 0);
}

// ---------------------------------------------------------------------------
// Split-K GEMM into fp32 partials.
// Concatenated K-space [0,K1) -> A1*B1t^T, [K1,K1+K2s) -> A2*B2t^T; block z
// owns K-chunk [z*CK,(z+1)*CK) (never crosses K1 by launch construction).
// Tile BM=128 x BN=256 x BK=32, 256 thr = 4 waves, each wave a 64x128 tile
// (4x8 grid of 16x16x32 f16 MFMAs, acc = 128 VGPRs). Double-buffered LDS
// (48 KB), one barrier per K-iter: async stage(k+1) overlaps MFMA(k).
// Rationale: 64x128/wave makes MFMA (621 cyc/CU-iter) the critical resource
// over LDS reads (578) and L2 staging (430); 64x64/wave was LDS-bound.
// ---------------------------------------------------------------------------
__global__ __launch_bounds__(256, 2) void gemm_splitk_kernel(
    const fp16_t* __restrict__ A1, const fp16_t* __restrict__ B1t, int K1,
    const fp16_t* __restrict__ A2, const fp16_t* __restrict__ B2t, int K2s,
    int CK, float* __restrict__ part, int Ntot)
{
    __shared__ __align__(16) fp16_t As[2][128][32];
    __shared__ __align__(16) fp16_t Bs[2][256][32];

    const int tid  = threadIdx.x;
    const int lane = tid & 63;
    const int w    = tid >> 6;         // wave 0..3
    const int wm   = w >> 1;           // m-half (64 rows)
    const int wn   = w & 1;            // n-half (128 cols)
    const int quad = lane >> 4;
    const int lrow = lane & 15;
    const int bm = blockIdx.y, bn = blockIdx.x, z = blockIdx.z;

    int koff = z * CK;
    const fp16_t* A; const fp16_t* Bt; int stride;
    if (koff < K1) { A = A1; Bt = B1t; stride = K1; }
    else           { A = A2; Bt = B2t; stride = K2s; koff -= K1; }

    // staging: each cp16 covers 16 rows x 32 fp16 (1 KB/wave).
    // lane -> (row = lane/4, col = (lane&3)*8). Wave w: A rows [32w,32w+32)
    // (2 insts), B rows [64w,64w+64) (4 insts).
    const int sr = lane >> 2;
    const int sc = (lane & 3) * 8;
    const fp16_t* ag = A  + (size_t)(bm * 128 + 32 * w + sr) * stride + koff + sc;
    const fp16_t* bg = Bt + (size_t)(bn * 256 + 64 * w + sr) * stride + koff + sc;
    const size_t st16 = (size_t)16 * stride;

    v4f acc[4][8] = {};

    const int iters = CK >> 5;

    // prologue: stage tile 0 into buffer 0
    async_cp16(ag,            &As[0][32 * w     ][0]);
    async_cp16(ag + st16,     &As[0][32 * w + 16][0]);
    async_cp16(bg,            &Bs[0][64 * w     ][0]);
    async_cp16(bg + st16,     &Bs[0][64 * w + 16][0]);
    async_cp16(bg + 2 * st16, &Bs[0][64 * w + 32][0]);
    async_cp16(bg + 3 * st16, &Bs[0][64 * w + 48][0]);
    ag += 32; bg += 32;

    for (int it = 0; it < iters; ++it) {
        __syncthreads();   // drains vmcnt -> buf (it&1) ready; prior ds_reads done
        if (it + 1 < iters) {
            const int nb = (it + 1) & 1;
            async_cp16(ag,            &As[nb][32 * w     ][0]);
            async_cp16(ag + st16,     &As[nb][32 * w + 16][0]);
            async_cp16(bg,            &Bs[nb][64 * w     ][0]);
            async_cp16(bg + st16,     &Bs[nb][64 * w + 16][0]);
            async_cp16(bg + 2 * st16, &Bs[nb][64 * w + 32][0]);
            async_cp16(bg + 3 * st16, &Bs[nb][64 * w + 48][0]);
            ag += 32; bg += 32;
        }
        const int cur = it & 1;
        v8h af[4], bv[8];
        #pragma unroll
        for (int fm = 0; fm < 4; ++fm)
            af[fm] = *(const v8h*)&As[cur][wm * 64 + fm * 16 + lrow][quad * 8];
        #pragma unroll
        for (int fn = 0; fn < 8; ++fn)
            bv[fn] = *(const v8h*)&Bs[cur][wn * 128 + fn * 16 + lrow][quad * 8];
        #pragma unroll
        for (int fm = 0; fm < 4; ++fm)
            #pragma unroll
            for (int fn = 0; fn < 8; ++fn)
                acc[fm][fn] = __builtin_amdgcn_mfma_f32_16x16x32_f16(
                    af[fm], bv[fn], acc[fm][fn], 0, 0, 0);
    }

    // write fp32 partials. C/D layout: col = lane&15, row = quad*4 + reg.
    float* po = part + (size_t)z * 1024 * Ntot;
    const int rowbase = bm * 128 + wm * 64 + quad * 4;
    const int colbase = bn * 256 + wn * 128;
    #pragma unroll
    for (int fn = 0; fn < 8; ++fn) {
        const int col = colbase + fn * 16 + lrow;
        #pragma unroll
        for (int fm = 0; fm < 4; ++fm) {
            const int row = rowbase + fm * 16;
            #pragma unroll
            for (int r = 0; r < 4; ++r)
                po[(size_t)(row + r) * Ntot + col] = acc[fm][fn][r];
        }
    }
}

// ---------------------------------------------------------------------------
// Sum nz partials + bias, then init/update + clip, dual-precision state write.
// 4 elements per thread, float4 loads. Ntot is a power of two.
// ---------------------------------------------------------------------------
__global__ __launch_bounds__(256) void reduce_update_kernel(
    const float* __restrict__ part, int nz,
    const float* __restrict__ bias, const float* __restrict__ s_old,
    float* __restrict__ outf, fp16_t* __restrict__ outb,
    int Ntot, int do_update, int total4)
{
    const int i = blockIdx.x * 256 + threadIdx.x;
    if (i >= total4) return;
    const size_t e = (size_t)i * 4;

    float4 a = *(const float4*)(part + e);
    for (int z = 1; z < nz; ++z) {
        const float4 p = *(const float4*)(part + (size_t)z * 1024 * Ntot + e);
        a.x += p.x; a.y += p.y; a.z += p.z; a.w += p.w;
    }
    const int col = (int)e & (Ntot - 1);
    const float4 bv = *(const float4*)(bias + col);
    float v[4] = {a.x + bv.x, a.y + bv.y, a.z + bv.z, a.w + bv.w};
    if (do_update) {
        const float4 so = *(const float4*)(s_old + e);
        v[0] = so.x + RELAX_LR * (v[0] - so.x);
        v[1] = so.y + RELAX_LR * (v[1] - so.y);
        v[2] = so.z + RELAX_LR * (v[2] - so.z);
        v[3] = so.w + RELAX_LR * (v[3] - so.w);
    }
    float4 o;
    o.x = fminf(fmaxf(v[0], 0.f), 1.f);
    o.y = fminf(fmaxf(v[1], 0.f), 1.f);
    o.z = fminf(fmaxf(v[2], 0.f), 1.f);
    o.w = fminf(fmaxf(v[3], 0.f), 1.f);
    *(float4*)(outf + e) = o;
    v4h h = {(fp16_t)o.x, (fp16_t)o.y, (fp16_t)o.z, (fp16_t)o.w};
    *(v4h*)(outb + e) = h;
}

// fp32 W [R,C] -> fp16 Wb [Rp,Cp] (optional) + fp16 WbT [Cp,Rp], zero-padded.
__global__ void conv_w_kernel(const float* __restrict__ W, int R, int C,
                              fp16_t* Wb, fp16_t* __restrict__ WbT,
                              int Rp, int Cp)
{
    __shared__ float t[32][33];
    const int tx = threadIdx.x & 31;
    const int ty = threadIdx.x >> 5;   // 0..7
    const int r0 = blockIdx.y * 32;
    const int c0 = blockIdx.x * 32;
    #pragma unroll
    for (int i = 0; i < 4; ++i) {
        const int r = r0 + ty + i * 8;
        const int c = c0 + tx;
        float v = 0.f;
        if (r < R && c < C) v = W[(size_t)r * C + c];
        t[ty + i * 8][tx] = v;
    }
    __syncthreads();
    if (Wb) {
        #pragma unroll
        for (int i = 0; i < 4; ++i) {
            const int r = r0 + ty + i * 8;
            const int c = c0 + tx;
            if (r < Rp && c < Cp) Wb[(size_t)r * Cp + c] = (fp16_t)t[ty + i * 8][tx];
        }
    }
    #pragma unroll
    for (int i = 0; i < 4; ++i) {
        const int cc = c0 + ty + i * 8;
        const int rr = r0 + tx;
        if (cc < Cp && rr < Rp) WbT[(size_t)cc * Rp + rr] = (fp16_t)t[tx][ty + i * 8];
    }
}

__global__ void conv_x_kernel(const float* __restrict__ x,
                              fp16_t* __restrict__ xb, fp16_t* __restrict__ rxb, int n)
{
    const int i = blockIdx.x * blockDim.x + threadIdx.x;
    if (i < n) {
        const float v = x[i];
        xb[i]  = (fp16_t)v;
        rxb[i] = (fp16_t)fminf(fmaxf(v, 0.f), 1.f);
    }
}

__global__ void pad_b4_kernel(const float* __restrict__ b4, float* __restrict__ b4p)
{
    const int i = blockIdx.x * blockDim.x + threadIdx.x;
    if (i < 1024) b4p[i] = (i < 1000) ? b4[i] : 0.f;
}

__global__ void out_copy_kernel(const float* __restrict__ s4f, float* __restrict__ out)
{
    const int i = blockIdx.x * blockDim.x + threadIdx.x;
    if (i < 1024 * 1000) {
        const int row = i / 1000;
        const int col = i - row * 1000;
        out[i] = s4f[(size_t)row * 1024 + col];
    }
}

extern "C" void kernel_launch(void* const* d_in, const int* in_sizes, int n_in,
                              void* d_out, int out_size, void* d_ws, size_t ws_size,
                              hipStream_t stream)
{
    const float* x  = (const float*)d_in[0];
    const float* W0 = (const float*)d_in[1];
    const float* W1 = (const float*)d_in[2];
    const float* W2 = (const float*)d_in[3];
    const float* W3 = (const float*)d_in[4];
    const float* b1 = (const float*)d_in[5];
    const float* b2 = (const float*)d_in[6];
    const float* b3 = (const float*)d_in[7];
    const float* b4 = (const float*)d_in[8];
    float* out = (float*)d_out;

    char* p = (char*)d_ws;
    auto alloc = [&](size_t bytes) {
        char* q = p;
        p += (bytes + 255) & ~(size_t)255;
        return q;
    };

    fp16_t* xb   = (fp16_t*)alloc((size_t)1024 * 2048 * 2);
    fp16_t* rxb  = (fp16_t*)alloc((size_t)1024 * 2048 * 2);
    fp16_t* Wb1  = (fp16_t*)alloc((size_t)2048 * 2048 * 2);
    fp16_t* Wb2  = (fp16_t*)alloc((size_t)2048 * 2048 * 2);
    fp16_t* Wb3  = (fp16_t*)alloc((size_t)2048 * 1024 * 2);   // padded cols
    fp16_t* WbT0 = (fp16_t*)alloc((size_t)2048 * 2048 * 2);
    fp16_t* WbT1 = (fp16_t*)alloc((size_t)2048 * 2048 * 2);
    fp16_t* WbT2 = (fp16_t*)alloc((size_t)2048 * 2048 * 2);
    fp16_t* WbT3 = (fp16_t*)alloc((size_t)1024 * 2048 * 2);   // padded rows
    float*  s1f  = (float*)alloc((size_t)1024 * 2048 * 4);
    float*  s2f  = (float*)alloc((size_t)1024 * 2048 * 4);
    float*  s3f  = (float*)alloc((size_t)1024 * 2048 * 4);
    float*  s4f  = (float*)alloc((size_t)1024 * 1024 * 4);
    fp16_t* s1b  = (fp16_t*)alloc((size_t)1024 * 2048 * 2);
    fp16_t* s2b  = (fp16_t*)alloc((size_t)1024 * 2048 * 2);
    fp16_t* s3b  = (fp16_t*)alloc((size_t)1024 * 2048 * 2);
    fp16_t* s4b  = (fp16_t*)alloc((size_t)1024 * 1024 * 2);
    float*  b4p  = (float*)alloc(1024 * 4);
    float*  part = (float*)alloc((size_t)4 * 1024 * 2048 * 4); // 32 MB, reused
    (void)ws_size; (void)in_sizes; (void)n_in; (void)out_size;

    // --- setup conversions ---
    conv_x_kernel<<<(1024 * 2048 + 255) / 256, 256, 0, stream>>>(x, xb, rxb, 1024 * 2048);
    pad_b4_kernel<<<4, 256, 0, stream>>>(b4, b4p);
    conv_w_kernel<<<dim3(64, 64), 256, 0, stream>>>(W0, 2048, 2048, nullptr, WbT0, 2048, 2048);
    conv_w_kernel<<<dim3(64, 64), 256, 0, stream>>>(W1, 2048, 2048, Wb1, WbT1, 2048, 2048);
    conv_w_kernel<<<dim3(64, 64), 256, 0, stream>>>(W2, 2048, 2048, Wb2, WbT2, 2048, 2048);
    conv_w_kernel<<<dim3(32, 64), 256, 0, stream>>>(W3, 2048, 1000, Wb3, WbT3, 2048, 1024);

    const dim3 blk(256);
    const int t4_2048 = 1024 * 2048 / 4;
    const int t4_1024 = 1024 * 1024 / 4;
    const int rg2048 = t4_2048 / 256;
    const int rg1024 = t4_1024 / 256;

    // BM=128 -> grid.y = 8. BN=256 -> grid.x = 8 (N=2048) / 4 (N=1024).
    // --- feedforward init (single GEMM, K=2048) ---
    gemm_splitk_kernel<<<dim3(8, 8, 4), blk, 0, stream>>>(xb,  WbT0, 2048, nullptr, nullptr, 0, 512, part, 2048);
    reduce_update_kernel<<<rg2048, blk, 0, stream>>>(part, 4, b1, nullptr, s1f, s1b, 2048, 0, t4_2048);
    gemm_splitk_kernel<<<dim3(8, 8, 4), blk, 0, stream>>>(s1b, WbT1, 2048, nullptr, nullptr, 0, 512, part, 2048);
    reduce_update_kernel<<<rg2048, blk, 0, stream>>>(part, 4, b2, nullptr, s2f, s2b, 2048, 0, t4_2048);
    gemm_splitk_kernel<<<dim3(8, 8, 4), blk, 0, stream>>>(s2b, WbT2, 2048, nullptr, nullptr, 0, 512, part, 2048);
    reduce_update_kernel<<<rg2048, blk, 0, stream>>>(part, 4, b3, nullptr, s3f, s3b, 2048, 0, t4_2048);
    gemm_splitk_kernel<<<dim3(4, 8, 8), blk, 0, stream>>>(s3b, WbT3, 2048, nullptr, nullptr, 0, 256, part, 1024);
    reduce_update_kernel<<<rg1024, blk, 0, stream>>>(part, 8, b4p, nullptr, s4f, s4b, 1024, 0, t4_1024);

    // --- 25 Gauss-Seidel sweeps (states post-rho => rho identity on them) ---
    for (int it = 0; it < 25; ++it) {
        // layer 1: rho(x)@W0 + s2@W1^T   (K-space 2048+2048, CK=1024, z=4)
        gemm_splitk_kernel<<<dim3(8, 8, 4), blk, 0, stream>>>(rxb, WbT0, 2048, s2b, Wb1, 2048, 1024, part, 2048);
        reduce_update_kernel<<<rg2048, blk, 0, stream>>>(part, 4, b1, s1f, s1f, s1b, 2048, 1, t4_2048);
        // layer 2: s1@W1 + s3@W2^T
        gemm_splitk_kernel<<<dim3(8, 8, 4), blk, 0, stream>>>(s1b, WbT1, 2048, s3b, Wb2, 2048, 1024, part, 2048);
        reduce_update_kernel<<<rg2048, blk, 0, stream>>>(part, 4, b2, s2f, s2f, s2b, 2048, 1, t4_2048);
        // layer 3: s2@W2 + s4@W3^T (K2=1024, CK=1024, z=3)
        gemm_splitk_kernel<<<dim3(8, 8, 3), blk, 0, stream>>>(s2b, WbT2, 2048, s4b, Wb3, 1024, 1024, part, 2048);
        reduce_update_kernel<<<rg2048, blk, 0, stream>>>(part, 3, b3, s3f, s3f, s3b, 2048, 1, t4_2048);
        // layer 4: s3@W3 (K=2048, CK=256, z=8)
        gemm_splitk_kernel<<<dim3(4, 8, 8), blk, 0, stream>>>(s3b, WbT3, 2048, nullptr, nullptr, 0, 256, part, 1024);
        reduce_update_kernel<<<rg1024, blk, 0, stream>>>(part, 8, b4p, s4f, s4f, s4b, 1024, 1, t4_1024);
    }

    // --- strip padding into d_out [1024,1000] ---
    out_copy_kernel<<<(1024 * 1000 + 255) / 256, 256, 0, stream>>>(s4f, out);
}

// Round 7
// 3219.002 us; speedup vs baseline: 1.3815x; 1.3815x over previous
//
#include <hip/hip_runtime.h>
#include <hip/hip_bf16.h>

typedef _Float16 fp16_t;
typedef _Float16 v8h __attribute__((ext_vector_type(8)));
typedef _Float16 v4h __attribute__((ext_vector_type(4)));
typedef float    v4f __attribute__((ext_vector_type(4)));

#define RELAX_LR 0.3f

// async global->LDS, 16B per lane. LDS dest = wave-uniform base + lane*16.
__device__ __forceinline__ void async_cp16(const void* g, void* l) {
    __builtin_amdgcn_global_load_lds(
        (const __attribute__((address_space(1))) void*)g,
        (__attribute__((address_space(3))) void*)l, 16, 0, 0);
}

// ---------------------------------------------------------------------------
// Split-K GEMM into fp32 partials.
// Concatenated K-space [0,K1) -> A1*B1t^T, [K1,K1+K2s) -> A2*B2t^T; block z
// owns K-chunk [z*CK,(z+1)*CK) (never crosses K1 by launch construction).
// Tile BM=128 x BN=128 x BK=64, 256 thr = 4 waves, each wave 64x64 (4x4 of
// 16x16x32 f16 MFMA). Double-buffered LDS, 64 KB -> exactly 2 blocks/CU;
// one barrier per BK=64 iter. BK=64 is laid out as 2 khalf sub-tiles of
// [128][32] so global_load_lds lane order stays contiguous (no padding).
// Cycle model/CU per block-iter: MFMA 620 cyc > LDS 512 cyc > exposed
// prefetch ~280 cyc; 2 resident blocks pack the stalls.
// ---------------------------------------------------------------------------
__global__ __launch_bounds__(256, 2) void gemm_splitk_kernel(
    const fp16_t* __restrict__ A1, const fp16_t* __restrict__ B1t, int K1,
    const fp16_t* __restrict__ A2, const fp16_t* __restrict__ B2t, int K2s,
    int CK, float* __restrict__ part, int Ntot)
{
    __shared__ __align__(16) fp16_t As[2][2][128][32];  // [stage][khalf][row][col]
    __shared__ __align__(16) fp16_t Bs[2][2][128][32];

    const int tid  = threadIdx.x;
    const int lane = tid & 63;
    const int w    = tid >> 6;         // wave 0..3
    const int wm   = w >> 1;           // m-half (64 rows)
    const int wn   = w & 1;            // n-half (64 cols)
    const int quad = lane >> 4;
    const int lrow = lane & 15;
    const int bm = blockIdx.y, bn = blockIdx.x, z = blockIdx.z;

    int koff = z * CK;
    const fp16_t* A; const fp16_t* Bt; int stride;
    if (koff < K1) { A = A1; Bt = B1t; stride = K1; }
    else           { A = A2; Bt = B2t; stride = K2s; koff -= K1; }

    // staging: each cp16 = 16 rows x 32 fp16 (1 KB/wave), lane -> (row=lane/4,
    // col=(lane&3)*8), matching LDS base + lane*16. Wave w owns rows
    // [32w,32w+32) of A and B for both khalves: 8 cp16/wave per stage.
    const int sr = lane >> 2;
    const int sc = (lane & 3) * 8;
    const fp16_t* ag = A  + (size_t)(bm * 128 + 32 * w + sr) * stride + koff + sc;
    const fp16_t* bg = Bt + (size_t)(bn * 128 + 32 * w + sr) * stride + koff + sc;
    const size_t st16 = (size_t)16 * stride;

    v4f acc[4][4] = {};

    const int iters = CK >> 6;         // BK = 64

    auto stage = [&](int buf, int kb) {
        const fp16_t* a0 = ag + kb;
        const fp16_t* b0 = bg + kb;
        async_cp16(a0,             &As[buf][0][32 * w     ][0]);
        async_cp16(a0 + st16,      &As[buf][0][32 * w + 16][0]);
        async_cp16(a0 + 32,        &As[buf][1][32 * w     ][0]);
        async_cp16(a0 + 32 + st16, &As[buf][1][32 * w + 16][0]);
        async_cp16(b0,             &Bs[buf][0][32 * w     ][0]);
        async_cp16(b0 + st16,      &Bs[buf][0][32 * w + 16][0]);
        async_cp16(b0 + 32,        &Bs[buf][1][32 * w     ][0]);
        async_cp16(b0 + 32 + st16, &Bs[buf][1][32 * w + 16][0]);
    };

    stage(0, 0);                       // prologue: tile 0 -> buffer 0

    for (int it = 0; it < iters; ++it) {
        __syncthreads();   // drains vmcnt -> buf (it&1) ready; prior ds_reads done
        if (it + 1 < iters) stage((it + 1) & 1, (it + 1) * 64);
        const int cur = it & 1;
        #pragma unroll
        for (int h = 0; h < 2; ++h) {
            v8h af[4], bv[4];
            #pragma unroll
            for (int fm = 0; fm < 4; ++fm)
                af[fm] = *(const v8h*)&As[cur][h][wm * 64 + fm * 16 + lrow][quad * 8];
            #pragma unroll
            for (int fn = 0; fn < 4; ++fn)
                bv[fn] = *(const v8h*)&Bs[cur][h][wn * 64 + fn * 16 + lrow][quad * 8];
            #pragma unroll
            for (int fm = 0; fm < 4; ++fm)
                #pragma unroll
                for (int fn = 0; fn < 4; ++fn)
                    acc[fm][fn] = __builtin_amdgcn_mfma_f32_16x16x32_f16(
                        af[fm], bv[fn], acc[fm][fn], 0, 0, 0);
        }
    }

    // write fp32 partials. C/D layout: col = lane&15, row = quad*4 + reg.
    float* po = part + (size_t)z * 1024 * Ntot;
    const int rowbase = bm * 128 + wm * 64 + quad * 4;
    const int colbase = bn * 128 + wn * 64;
    #pragma unroll
    for (int fn = 0; fn < 4; ++fn) {
        const int col = colbase + fn * 16 + lrow;
        #pragma unroll
        for (int fm = 0; fm < 4; ++fm) {
            const int row = rowbase + fm * 16;
            #pragma unroll
            for (int r = 0; r < 4; ++r)
                po[(size_t)(row + r) * Ntot + col] = acc[fm][fn][r];
        }
    }
}

// ---------------------------------------------------------------------------
// Sum nz partials + bias, then init/update + clip, dual-precision state write.
// 4 elements per thread, float4 loads. Ntot is a power of two.
// ---------------------------------------------------------------------------
__global__ __launch_bounds__(256) void reduce_update_kernel(
    const float* __restrict__ part, int nz,
    const float* __restrict__ bias, const float* __restrict__ s_old,
    float* __restrict__ outf, fp16_t* __restrict__ outb,
    int Ntot, int do_update, int total4)
{
    const int i = blockIdx.x * 256 + threadIdx.x;
    if (i >= total4) return;
    const size_t e = (size_t)i * 4;

    float4 a = *(const float4*)(part + e);
    for (int z = 1; z < nz; ++z) {
        const float4 p = *(const float4*)(part + (size_t)z * 1024 * Ntot + e);
        a.x += p.x; a.y += p.y; a.z += p.z; a.w += p.w;
    }
    const int col = (int)e & (Ntot - 1);
    const float4 bv = *(const float4*)(bias + col);
    float v[4] = {a.x + bv.x, a.y + bv.y, a.z + bv.z, a.w + bv.w};
    if (do_update) {
        const float4 so = *(const float4*)(s_old + e);
        v[0] = so.x + RELAX_LR * (v[0] - so.x);
        v[1] = so.y + RELAX_LR * (v[1] - so.y);
        v[2] = so.z + RELAX_LR * (v[2] - so.z);
        v[3] = so.w + RELAX_LR * (v[3] - so.w);
    }
    float4 o;
    o.x = fminf(fmaxf(v[0], 0.f), 1.f);
    o.y = fminf(fmaxf(v[1], 0.f), 1.f);
    o.z = fminf(fmaxf(v[2], 0.f), 1.f);
    o.w = fminf(fmaxf(v[3], 0.f), 1.f);
    *(float4*)(outf + e) = o;
    v4h h = {(fp16_t)o.x, (fp16_t)o.y, (fp16_t)o.z, (fp16_t)o.w};
    *(v4h*)(outb + e) = h;
}

// fp32 W [R,C] -> fp16 Wb [Rp,Cp] (optional) + fp16 WbT [Cp,Rp], zero-padded.
__global__ void conv_w_kernel(const float* __restrict__ W, int R, int C,
                              fp16_t* Wb, fp16_t* __restrict__ WbT,
                              int Rp, int Cp)
{
    __shared__ float t[32][33];
    const int tx = threadIdx.x & 31;
    const int ty = threadIdx.x >> 5;   // 0..7
    const int r0 = blockIdx.y * 32;
    const int c0 = blockIdx.x * 32;
    #pragma unroll
    for (int i = 0; i < 4; ++i) {
        const int r = r0 + ty + i * 8;
        const int c = c0 + tx;
        float v = 0.f;
        if (r < R && c < C) v = W[(size_t)r * C + c];
        t[ty + i * 8][tx] = v;
    }
    __syncthreads();
    if (Wb) {
        #pragma unroll
        for (int i = 0; i < 4; ++i) {
            const int r = r0 + ty + i * 8;
            const int c = c0 + tx;
            if (r < Rp && c < Cp) Wb[(size_t)r * Cp + c] = (fp16_t)t[ty + i * 8][tx];
        }
    }
    #pragma unroll
    for (int i = 0; i < 4; ++i) {
        const int cc = c0 + ty + i * 8;
        const int rr = r0 + tx;
        if (cc < Cp && rr < Rp) WbT[(size_t)cc * Rp + rr] = (fp16_t)t[tx][ty + i * 8];
    }
}

__global__ void conv_x_kernel(const float* __restrict__ x,
                              fp16_t* __restrict__ xb, fp16_t* __restrict__ rxb, int n)
{
    const int i = blockIdx.x * blockDim.x + threadIdx.x;
    if (i < n) {
        const float v = x[i];
        xb[i]  = (fp16_t)v;
        rxb[i] = (fp16_t)fminf(fmaxf(v, 0.f), 1.f);
    }
}

__global__ void pad_b4_kernel(const float* __restrict__ b4, float* __restrict__ b4p)
{
    const int i = blockIdx.x * blockDim.x + threadIdx.x;
    if (i < 1024) b4p[i] = (i < 1000) ? b4[i] : 0.f;
}

__global__ void out_copy_kernel(const float* __restrict__ s4f, float* __restrict__ out)
{
    const int i = blockIdx.x * blockDim.x + threadIdx.x;
    if (i < 1024 * 1000) {
        const int row = i / 1000;
        const int col = i - row * 1000;
        out[i] = s4f[(size_t)row * 1024 + col];
    }
}

extern "C" void kernel_launch(void* const* d_in, const int* in_sizes, int n_in,
                              void* d_out, int out_size, void* d_ws, size_t ws_size,
                              hipStream_t stream)
{
    const float* x  = (const float*)d_in[0];
    const float* W0 = (const float*)d_in[1];
    const float* W1 = (const float*)d_in[2];
    const float* W2 = (const float*)d_in[3];
    const float* W3 = (const float*)d_in[4];
    const float* b1 = (const float*)d_in[5];
    const float* b2 = (const float*)d_in[6];
    const float* b3 = (const float*)d_in[7];
    const float* b4 = (const float*)d_in[8];
    float* out = (float*)d_out;

    char* p = (char*)d_ws;
    auto alloc = [&](size_t bytes) {
        char* q = p;
        p += (bytes + 255) & ~(size_t)255;
        return q;
    };

    fp16_t* xb   = (fp16_t*)alloc((size_t)1024 * 2048 * 2);
    fp16_t* rxb  = (fp16_t*)alloc((size_t)1024 * 2048 * 2);
    fp16_t* Wb1  = (fp16_t*)alloc((size_t)2048 * 2048 * 2);
    fp16_t* Wb2  = (fp16_t*)alloc((size_t)2048 * 2048 * 2);
    fp16_t* Wb3  = (fp16_t*)alloc((size_t)2048 * 1024 * 2);   // padded cols
    fp16_t* WbT0 = (fp16_t*)alloc((size_t)2048 * 2048 * 2);
    fp16_t* WbT1 = (fp16_t*)alloc((size_t)2048 * 2048 * 2);
    fp16_t* WbT2 = (fp16_t*)alloc((size_t)2048 * 2048 * 2);
    fp16_t* WbT3 = (fp16_t*)alloc((size_t)1024 * 2048 * 2);   // padded rows
    float*  s1f  = (float*)alloc((size_t)1024 * 2048 * 4);
    float*  s2f  = (float*)alloc((size_t)1024 * 2048 * 4);
    float*  s3f  = (float*)alloc((size_t)1024 * 2048 * 4);
    float*  s4f  = (float*)alloc((size_t)1024 * 1024 * 4);
    fp16_t* s1b  = (fp16_t*)alloc((size_t)1024 * 2048 * 2);
    fp16_t* s2b  = (fp16_t*)alloc((size_t)1024 * 2048 * 2);
    fp16_t* s3b  = (fp16_t*)alloc((size_t)1024 * 2048 * 2);
    fp16_t* s4b  = (fp16_t*)alloc((size_t)1024 * 1024 * 2);
    float*  b4p  = (float*)alloc(1024 * 4);
    float*  part = (float*)alloc((size_t)4 * 1024 * 2048 * 4); // 32 MB, reused
    (void)ws_size; (void)in_sizes; (void)n_in; (void)out_size;

    // --- setup conversions ---
    conv_x_kernel<<<(1024 * 2048 + 255) / 256, 256, 0, stream>>>(x, xb, rxb, 1024 * 2048);
    pad_b4_kernel<<<4, 256, 0, stream>>>(b4, b4p);
    conv_w_kernel<<<dim3(64, 64), 256, 0, stream>>>(W0, 2048, 2048, nullptr, WbT0, 2048, 2048);
    conv_w_kernel<<<dim3(64, 64), 256, 0, stream>>>(W1, 2048, 2048, Wb1, WbT1, 2048, 2048);
    conv_w_kernel<<<dim3(64, 64), 256, 0, stream>>>(W2, 2048, 2048, Wb2, WbT2, 2048, 2048);
    conv_w_kernel<<<dim3(32, 64), 256, 0, stream>>>(W3, 2048, 1000, Wb3, WbT3, 2048, 1024);

    const dim3 blk(256);
    const int t4_2048 = 1024 * 2048 / 4;
    const int t4_1024 = 1024 * 1024 / 4;
    const int rg2048 = t4_2048 / 256;
    const int rg1024 = t4_1024 / 256;

    // BM=128, BN=128: grid (16, 8, z) for N=2048; (8, 8, z) for N=1024.
    // z=4 -> 512 blocks = 2 blocks/CU (64 KB LDS each).
    // --- feedforward init (single GEMM, K=2048, CK=512 -> 8 BK-iters) ---
    gemm_splitk_kernel<<<dim3(16, 8, 4), blk, 0, stream>>>(xb,  WbT0, 2048, nullptr, nullptr, 0, 512, part, 2048);
    reduce_update_kernel<<<rg2048, blk, 0, stream>>>(part, 4, b1, nullptr, s1f, s1b, 2048, 0, t4_2048);
    gemm_splitk_kernel<<<dim3(16, 8, 4), blk, 0, stream>>>(s1b, WbT1, 2048, nullptr, nullptr, 0, 512, part, 2048);
    reduce_update_kernel<<<rg2048, blk, 0, stream>>>(part, 4, b2, nullptr, s2f, s2b, 2048, 0, t4_2048);
    gemm_splitk_kernel<<<dim3(16, 8, 4), blk, 0, stream>>>(s2b, WbT2, 2048, nullptr, nullptr, 0, 512, part, 2048);
    reduce_update_kernel<<<rg2048, blk, 0, stream>>>(part, 4, b3, nullptr, s3f, s3b, 2048, 0, t4_2048);
    gemm_splitk_kernel<<<dim3(8, 8, 8), blk, 0, stream>>>(s3b, WbT3, 2048, nullptr, nullptr, 0, 256, part, 1024);
    reduce_update_kernel<<<rg1024, blk, 0, stream>>>(part, 8, b4p, nullptr, s4f, s4b, 1024, 0, t4_1024);

    // --- 25 Gauss-Seidel sweeps (states post-rho => rho identity on them) ---
    for (int it = 0; it < 25; ++it) {
        // layer 1: rho(x)@W0 + s2@W1^T   (K-space 2048+2048, CK=1024, z=4)
        gemm_splitk_kernel<<<dim3(16, 8, 4), blk, 0, stream>>>(rxb, WbT0, 2048, s2b, Wb1, 2048, 1024, part, 2048);
        reduce_update_kernel<<<rg2048, blk, 0, stream>>>(part, 4, b1, s1f, s1f, s1b, 2048, 1, t4_2048);
        // layer 2: s1@W1 + s3@W2^T
        gemm_splitk_kernel<<<dim3(16, 8, 4), blk, 0, stream>>>(s1b, WbT1, 2048, s3b, Wb2, 2048, 1024, part, 2048);
        reduce_update_kernel<<<rg2048, blk, 0, stream>>>(part, 4, b2, s2f, s2f, s2b, 2048, 1, t4_2048);
        // layer 3: s2@W2 + s4@W3^T (K2=1024, CK=1024, z=3)
        gemm_splitk_kernel<<<dim3(16, 8, 3), blk, 0, stream>>>(s2b, WbT2, 2048, s4b, Wb3, 1024, 1024, part, 2048);
        reduce_update_kernel<<<rg2048, blk, 0, stream>>>(part, 3, b3, s3f, s3f, s3b, 2048, 1, t4_2048);
        // layer 4: s3@W3 (K=2048, CK=256 -> 4 BK-iters, z=8)
        gemm_splitk_kernel<<<dim3(8, 8, 8), blk, 0, stream>>>(s3b, WbT3, 2048, nullptr, nullptr, 0, 256, part, 1024);
        reduce_update_kernel<<<rg1024, blk, 0, stream>>>(part, 8, b4p, s4f, s4f, s4b, 1024, 1, t4_1024);
    }

    // --- strip padding into d_out [1024,1000] ---
    out_copy_kernel<<<(1024 * 1000 + 255) / 256, 256, 0, stream>>>(s4f, out);
}

// Round 8
// 2954.521 us; speedup vs baseline: 1.5051x; 1.0895x over previous
//
#include <hip/hip_runtime.h>
#include <hip/hip_bf16.h>

typedef _Float16 fp16_t;
typedef _Float16 v8h __attribute__((ext_vector_type(8)));
typedef _Float16 v4h __attribute__((ext_vector_type(4)));
typedef float    v4f __attribute__((ext_vector_type(4)));

#define RELAX_LR 0.3f

// async global->LDS, 16B per lane. LDS dest = wave-uniform base + lane*16.
__device__ __forceinline__ void async_cp16(const void* g, void* l) {
    __builtin_amdgcn_global_load_lds(
        (const __attribute__((address_space(1))) void*)g,
        (__attribute__((address_space(3))) void*)l, 16, 0, 0);
}

// ---------------------------------------------------------------------------
// Split-K GEMM into fp16 partials (fp32 MFMA accumulate, one rounding at
// store; |partial| ~ 2 -> abs err ~2e-4, 40x below the pipeline error floor).
// Concatenated K-space [0,K1) -> A1*B1t^T, [K1,K1+K2s) -> A2*B2t^T; block z
// owns K-chunk [z*CK,(z+1)*CK) (never crosses K1 by launch construction).
// Tile BM=128 x BN=128 x BK=64, 256 thr = 4 waves, each wave 64x64 (4x4 of
// 16x16x32 f16 MFMA). Double-buffered LDS, 64 KB -> exactly 2 blocks/CU;
// one barrier per BK=64 iter; BK laid out as 2 khalf [128][32] sub-tiles so
// global_load_lds lane order stays contiguous.
// ---------------------------------------------------------------------------
__global__ __launch_bounds__(256, 2) void gemm_splitk_kernel(
    const fp16_t* __restrict__ A1, const fp16_t* __restrict__ B1t, int K1,
    const fp16_t* __restrict__ A2, const fp16_t* __restrict__ B2t, int K2s,
    int CK, fp16_t* __restrict__ part, int Ntot)
{
    __shared__ __align__(16) fp16_t As[2][2][128][32];  // [stage][khalf][row][col]
    __shared__ __align__(16) fp16_t Bs[2][2][128][32];

    const int tid  = threadIdx.x;
    const int lane = tid & 63;
    const int w    = tid >> 6;         // wave 0..3
    const int wm   = w >> 1;           // m-half (64 rows)
    const int wn   = w & 1;            // n-half (64 cols)
    const int quad = lane >> 4;
    const int lrow = lane & 15;
    const int bm = blockIdx.y, bn = blockIdx.x, z = blockIdx.z;

    int koff = z * CK;
    const fp16_t* A; const fp16_t* Bt; int stride;
    if (koff < K1) { A = A1; Bt = B1t; stride = K1; }
    else           { A = A2; Bt = B2t; stride = K2s; koff -= K1; }

    // staging: each cp16 = 16 rows x 32 fp16 (1 KB/wave), lane -> (row=lane/4,
    // col=(lane&3)*8), matching LDS base + lane*16. Wave w owns rows
    // [32w,32w+32) of A and B for both khalves: 8 cp16/wave per stage.
    const int sr = lane >> 2;
    const int sc = (lane & 3) * 8;
    const fp16_t* ag = A  + (size_t)(bm * 128 + 32 * w + sr) * stride + koff + sc;
    const fp16_t* bg = Bt + (size_t)(bn * 128 + 32 * w + sr) * stride + koff + sc;
    const size_t st16 = (size_t)16 * stride;

    v4f acc[4][4] = {};

    const int iters = CK >> 6;         // BK = 64

    auto stage = [&](int buf, int kb) {
        const fp16_t* a0 = ag + kb;
        const fp16_t* b0 = bg + kb;
        async_cp16(a0,             &As[buf][0][32 * w     ][0]);
        async_cp16(a0 + st16,      &As[buf][0][32 * w + 16][0]);
        async_cp16(a0 + 32,        &As[buf][1][32 * w     ][0]);
        async_cp16(a0 + 32 + st16, &As[buf][1][32 * w + 16][0]);
        async_cp16(b0,             &Bs[buf][0][32 * w     ][0]);
        async_cp16(b0 + st16,      &Bs[buf][0][32 * w + 16][0]);
        async_cp16(b0 + 32,        &Bs[buf][1][32 * w     ][0]);
        async_cp16(b0 + 32 + st16, &Bs[buf][1][32 * w + 16][0]);
    };

    stage(0, 0);                       // prologue: tile 0 -> buffer 0

    for (int it = 0; it < iters; ++it) {
        __syncthreads();   // drains vmcnt -> buf (it&1) ready; prior ds_reads done
        if (it + 1 < iters) stage((it + 1) & 1, (it + 1) * 64);
        const int cur = it & 1;
        #pragma unroll
        for (int h = 0; h < 2; ++h) {
            v8h af[4], bv[4];
            #pragma unroll
            for (int fm = 0; fm < 4; ++fm)
                af[fm] = *(const v8h*)&As[cur][h][wm * 64 + fm * 16 + lrow][quad * 8];
            #pragma unroll
            for (int fn = 0; fn < 4; ++fn)
                bv[fn] = *(const v8h*)&Bs[cur][h][wn * 64 + fn * 16 + lrow][quad * 8];
            #pragma unroll
            for (int fm = 0; fm < 4; ++fm)
                #pragma unroll
                for (int fn = 0; fn < 4; ++fn)
                    acc[fm][fn] = __builtin_amdgcn_mfma_f32_16x16x32_f16(
                        af[fm], bv[fn], acc[fm][fn], 0, 0, 0);
        }
    }

    // write fp16 partials. C/D layout: col = lane&15, row = quad*4 + reg.
    fp16_t* po = part + (size_t)z * 1024 * Ntot;
    const int rowbase = bm * 128 + wm * 64 + quad * 4;
    const int colbase = bn * 128 + wn * 64;
    #pragma unroll
    for (int fn = 0; fn < 4; ++fn) {
        const int col = colbase + fn * 16 + lrow;
        #pragma unroll
        for (int fm = 0; fm < 4; ++fm) {
            const int row = rowbase + fm * 16;
            #pragma unroll
            for (int r = 0; r < 4; ++r)
                po[(size_t)(row + r) * Ntot + col] = (fp16_t)acc[fm][fn][r];
        }
    }
}

// ---------------------------------------------------------------------------
// Sum nz fp16 partial slices (fp32 accumulate) + bias, init/update + clip,
// dual-precision state write. 8 elements/thread, 16B loads.
// ---------------------------------------------------------------------------
__global__ __launch_bounds__(256) void reduce_update_kernel(
    const fp16_t* __restrict__ part, int nz,
    const float* __restrict__ bias, const float* __restrict__ s_old,
    float* __restrict__ outf, fp16_t* __restrict__ outb,
    int Ntot, int do_update, int total8)
{
    const int i = blockIdx.x * 256 + threadIdx.x;
    if (i >= total8) return;
    const size_t e = (size_t)i * 8;

    float v[8];
    {
        const v8h p0 = *(const v8h*)(part + e);
        #pragma unroll
        for (int j = 0; j < 8; ++j) v[j] = (float)p0[j];
    }
    for (int z = 1; z < nz; ++z) {
        const v8h p = *(const v8h*)(part + (size_t)z * 1024 * Ntot + e);
        #pragma unroll
        for (int j = 0; j < 8; ++j) v[j] += (float)p[j];
    }
    const int col = (int)e & (Ntot - 1);
    const float4 b0 = *(const float4*)(bias + col);
    const float4 b1 = *(const float4*)(bias + col + 4);
    v[0] += b0.x; v[1] += b0.y; v[2] += b0.z; v[3] += b0.w;
    v[4] += b1.x; v[5] += b1.y; v[6] += b1.z; v[7] += b1.w;
    if (do_update) {
        const float4 s0 = *(const float4*)(s_old + e);
        const float4 s1 = *(const float4*)(s_old + e + 4);
        const float so[8] = {s0.x, s0.y, s0.z, s0.w, s1.x, s1.y, s1.z, s1.w};
        #pragma unroll
        for (int j = 0; j < 8; ++j) v[j] = so[j] + RELAX_LR * (v[j] - so[j]);
    }
    float4 o0, o1;
    #pragma unroll
    for (int j = 0; j < 8; ++j) v[j] = fminf(fmaxf(v[j], 0.f), 1.f);
    o0.x = v[0]; o0.y = v[1]; o0.z = v[2]; o0.w = v[3];
    o1.x = v[4]; o1.y = v[5]; o1.z = v[6]; o1.w = v[7];
    *(float4*)(outf + e)     = o0;
    *(float4*)(outf + e + 4) = o1;
    v8h h;
    #pragma unroll
    for (int j = 0; j < 8; ++j) h[j] = (fp16_t)v[j];
    *(v8h*)(outb + e) = h;
}

// fp32 W [R,C] -> fp16 Wb [Rp,Cp] (optional) + fp16 WbT [Cp,Rp], zero-padded.
__global__ void conv_w_kernel(const float* __restrict__ W, int R, int C,
                              fp16_t* Wb, fp16_t* __restrict__ WbT,
                              int Rp, int Cp)
{
    __shared__ float t[32][33];
    const int tx = threadIdx.x & 31;
    const int ty = threadIdx.x >> 5;   // 0..7
    const int r0 = blockIdx.y * 32;
    const int c0 = blockIdx.x * 32;
    #pragma unroll
    for (int i = 0; i < 4; ++i) {
        const int r = r0 + ty + i * 8;
        const int c = c0 + tx;
        float v = 0.f;
        if (r < R && c < C) v = W[(size_t)r * C + c];
        t[ty + i * 8][tx] = v;
    }
    __syncthreads();
    if (Wb) {
        #pragma unroll
        for (int i = 0; i < 4; ++i) {
            const int r = r0 + ty + i * 8;
            const int c = c0 + tx;
            if (r < Rp && c < Cp) Wb[(size_t)r * Cp + c] = (fp16_t)t[ty + i * 8][tx];
        }
    }
    #pragma unroll
    for (int i = 0; i < 4; ++i) {
        const int cc = c0 + ty + i * 8;
        const int rr = r0 + tx;
        if (cc < Cp && rr < Rp) WbT[(size_t)cc * Rp + rr] = (fp16_t)t[tx][ty + i * 8];
    }
}

__global__ void conv_x_kernel(const float* __restrict__ x,
                              fp16_t* __restrict__ xb, fp16_t* __restrict__ rxb, int n)
{
    const int i = blockIdx.x * blockDim.x + threadIdx.x;
    if (i < n) {
        const float v = x[i];
        xb[i]  = (fp16_t)v;
        rxb[i] = (fp16_t)fminf(fmaxf(v, 0.f), 1.f);
    }
}

__global__ void pad_b4_kernel(const float* __restrict__ b4, float* __restrict__ b4p)
{
    const int i = blockIdx.x * blockDim.x + threadIdx.x;
    if (i < 1024) b4p[i] = (i < 1000) ? b4[i] : 0.f;
}

__global__ void out_copy_kernel(const float* __restrict__ s4f, float* __restrict__ out)
{
    const int i = blockIdx.x * blockDim.x + threadIdx.x;
    if (i < 1024 * 1000) {
        const int row = i / 1000;
        const int col = i - row * 1000;
        out[i] = s4f[(size_t)row * 1024 + col];
    }
}

extern "C" void kernel_launch(void* const* d_in, const int* in_sizes, int n_in,
                              void* d_out, int out_size, void* d_ws, size_t ws_size,
                              hipStream_t stream)
{
    const float* x  = (const float*)d_in[0];
    const float* W0 = (const float*)d_in[1];
    const float* W1 = (const float*)d_in[2];
    const float* W2 = (const float*)d_in[3];
    const float* W3 = (const float*)d_in[4];
    const float* b1 = (const float*)d_in[5];
    const float* b2 = (const float*)d_in[6];
    const float* b3 = (const float*)d_in[7];
    const float* b4 = (const float*)d_in[8];
    float* out = (float*)d_out;

    char* p = (char*)d_ws;
    auto alloc = [&](size_t bytes) {
        char* q = p;
        p += (bytes + 255) & ~(size_t)255;
        return q;
    };

    fp16_t* xb   = (fp16_t*)alloc((size_t)1024 * 2048 * 2);
    fp16_t* rxb  = (fp16_t*)alloc((size_t)1024 * 2048 * 2);
    fp16_t* Wb1  = (fp16_t*)alloc((size_t)2048 * 2048 * 2);
    fp16_t* Wb2  = (fp16_t*)alloc((size_t)2048 * 2048 * 2);
    fp16_t* Wb3  = (fp16_t*)alloc((size_t)2048 * 1024 * 2);   // padded cols
    fp16_t* WbT0 = (fp16_t*)alloc((size_t)2048 * 2048 * 2);
    fp16_t* WbT1 = (fp16_t*)alloc((size_t)2048 * 2048 * 2);
    fp16_t* WbT2 = (fp16_t*)alloc((size_t)2048 * 2048 * 2);
    fp16_t* WbT3 = (fp16_t*)alloc((size_t)1024 * 2048 * 2);   // padded rows
    float*  s1f  = (float*)alloc((size_t)1024 * 2048 * 4);
    float*  s2f  = (float*)alloc((size_t)1024 * 2048 * 4);
    float*  s3f  = (float*)alloc((size_t)1024 * 2048 * 4);
    float*  s4f  = (float*)alloc((size_t)1024 * 1024 * 4);
    fp16_t* s1b  = (fp16_t*)alloc((size_t)1024 * 2048 * 2);
    fp16_t* s2b  = (fp16_t*)alloc((size_t)1024 * 2048 * 2);
    fp16_t* s3b  = (fp16_t*)alloc((size_t)1024 * 2048 * 2);
    fp16_t* s4b  = (fp16_t*)alloc((size_t)1024 * 1024 * 2);
    float*  b4p  = (float*)alloc(1024 * 4);
    fp16_t* part = (fp16_t*)alloc((size_t)4 * 1024 * 2048 * 2); // 16 MB, reused
    (void)ws_size; (void)in_sizes; (void)n_in; (void)out_size;

    // --- setup conversions ---
    conv_x_kernel<<<(1024 * 2048 + 255) / 256, 256, 0, stream>>>(x, xb, rxb, 1024 * 2048);
    pad_b4_kernel<<<4, 256, 0, stream>>>(b4, b4p);
    conv_w_kernel<<<dim3(64, 64), 256, 0, stream>>>(W0, 2048, 2048, nullptr, WbT0, 2048, 2048);
    conv_w_kernel<<<dim3(64, 64), 256, 0, stream>>>(W1, 2048, 2048, Wb1, WbT1, 2048, 2048);
    conv_w_kernel<<<dim3(64, 64), 256, 0, stream>>>(W2, 2048, 2048, Wb2, WbT2, 2048, 2048);
    conv_w_kernel<<<dim3(32, 64), 256, 0, stream>>>(W3, 2048, 1000, Wb3, WbT3, 2048, 1024);

    const dim3 blk(256);
    const int t8_2048 = 1024 * 2048 / 8;
    const int t8_1024 = 1024 * 1024 / 8;
    const int rg2048 = t8_2048 / 256;   // 1024 blocks
    const int rg1024 = t8_1024 / 256;   // 512 blocks

    // BM=128, BN=128: grid (16, 8, z) for N=2048; (8, 8, z) for N=1024.
    // z=4 -> 512 blocks = 2 blocks/CU (64 KB LDS each).
    // --- feedforward init (single GEMM, K=2048, CK=512 -> 8 BK-iters) ---
    gemm_splitk_kernel<<<dim3(16, 8, 4), blk, 0, stream>>>(xb,  WbT0, 2048, nullptr, nullptr, 0, 512, part, 2048);
    reduce_update_kernel<<<rg2048, blk, 0, stream>>>(part, 4, b1, nullptr, s1f, s1b, 2048, 0, t8_2048);
    gemm_splitk_kernel<<<dim3(16, 8, 4), blk, 0, stream>>>(s1b, WbT1, 2048, nullptr, nullptr, 0, 512, part, 2048);
    reduce_update_kernel<<<rg2048, blk, 0, stream>>>(part, 4, b2, nullptr, s2f, s2b, 2048, 0, t8_2048);
    gemm_splitk_kernel<<<dim3(16, 8, 4), blk, 0, stream>>>(s2b, WbT2, 2048, nullptr, nullptr, 0, 512, part, 2048);
    reduce_update_kernel<<<rg2048, blk, 0, stream>>>(part, 4, b3, nullptr, s3f, s3b, 2048, 0, t8_2048);
    gemm_splitk_kernel<<<dim3(8, 8, 8), blk, 0, stream>>>(s3b, WbT3, 2048, nullptr, nullptr, 0, 256, part, 1024);
    reduce_update_kernel<<<rg1024, blk, 0, stream>>>(part, 8, b4p, nullptr, s4f, s4b, 1024, 0, t8_1024);

    // --- 25 Gauss-Seidel sweeps (states post-rho => rho identity on them) ---
    for (int it = 0; it < 25; ++it) {
        // layer 1: rho(x)@W0 + s2@W1^T   (K-space 2048+2048, CK=1024, z=4)
        gemm_splitk_kernel<<<dim3(16, 8, 4), blk, 0, stream>>>(rxb, WbT0, 2048, s2b, Wb1, 2048, 1024, part, 2048);
        reduce_update_kernel<<<rg2048, blk, 0, stream>>>(part, 4, b1, s1f, s1f, s1b, 2048, 1, t8_2048);
        // layer 2: s1@W1 + s3@W2^T
        gemm_splitk_kernel<<<dim3(16, 8, 4), blk, 0, stream>>>(s1b, WbT1, 2048, s3b, Wb2, 2048, 1024, part, 2048);
        reduce_update_kernel<<<rg2048, blk, 0, stream>>>(part, 4, b2, s2f, s2f, s2b, 2048, 1, t8_2048);
        // layer 3: s2@W2 + s4@W3^T (K2=1024, CK=1024, z=3)
        gemm_splitk_kernel<<<dim3(16, 8, 3), blk, 0, stream>>>(s2b, WbT2, 2048, s4b, Wb3, 1024, 1024, part, 2048);
        reduce_update_kernel<<<rg2048, blk, 0, stream>>>(part, 3, b3, s3f, s3f, s3b, 2048, 1, t8_2048);
        // layer 4: s3@W3 (K=2048, CK=256 -> 4 BK-iters, z=8)
        gemm_splitk_kernel<<<dim3(8, 8, 8), blk, 0, stream>>>(s3b, WbT3, 2048, nullptr, nullptr, 0, 256, part, 1024);
        reduce_update_kernel<<<rg1024, blk, 0, stream>>>(part, 8, b4p, s4f, s4f, s4b, 1024, 1, t8_1024);
    }

    // --- strip padding into d_out [1024,1000] ---
    out_copy_kernel<<<(1024 * 1000 + 255) / 256, 256, 0, stream>>>(s4f, out);
}